// Round 8
// baseline (307.909 us; speedup 1.0000x reference)
//
#include <hip/hip_runtime.h>
#include <hip/hip_bf16.h>
#include <stdint.h>

#define TOKENS 8192
#define NOUT   4096
#define KIN    4096

#define BM 256
#define BN 256
#define BK 64
#define NT (KIN / BK)   // 64 K-tiles

typedef __attribute__((ext_vector_type(8)))  short bf16x8;
typedef __attribute__((ext_vector_type(4)))  float f32x4;
typedef __attribute__((ext_vector_type(16))) float f32x16;

__device__ __forceinline__ uint32_t rotl32(uint32_t x, int r) {
  return (x << r) | (x >> (32 - r));
}

__device__ __forceinline__ uint16_t f2bf_rne(float f) {
  uint32_t u = __float_as_uint(f);
  u += 0x7FFFu + ((u >> 16) & 1u);
  return (uint16_t)(u >> 16);
}

// Threefry-2x32, 20 rounds — JAX PRNG core.
__device__ __forceinline__ void threefry2x32(uint32_t k0, uint32_t k1,
                                             uint32_t c0, uint32_t c1,
                                             uint32_t& o0, uint32_t& o1) {
  uint32_t ks2 = 0x1BD11BDAu ^ k0 ^ k1;
  uint32_t x0 = c0 + k0;
  uint32_t x1 = c1 + k1;
#define TFR(r) { x0 += x1; x1 = rotl32(x1, (r)); x1 ^= x0; }
  TFR(13) TFR(15) TFR(26) TFR(6)
  x0 += k1;  x1 += ks2 + 1u;
  TFR(17) TFR(29) TFR(16) TFR(24)
  x0 += ks2; x1 += k0 + 2u;
  TFR(13) TFR(15) TFR(26) TFR(6)
  x0 += k0;  x1 += k1 + 3u;
  TFR(17) TFR(29) TFR(16) TFR(24)
  x0 += k1;  x1 += ks2 + 4u;
  TFR(13) TFR(15) TFR(26) TFR(6)
  x0 += ks2; x1 += k0 + 5u;
#undef TFR
  o0 = x0; o1 = x1;
}

// Fused prep: blocks [0, 65536) hydrate W (partitionable threefry —
// VERIFIED round 3); blocks [65536, 81920) convert x fp32->bf16.
__global__ void prep_kernel(const float* __restrict__ x,
                            uint16_t* __restrict__ xb,
                            uint16_t* __restrict__ W,
                            const int* __restrict__ seed_ptr) {
  uint32_t b = blockIdx.x;
  if (b < 65536u) {
    uint32_t k1 = (uint32_t)(*seed_ptr);            // key = (0, seed)
    uint32_t j = b * 256u + threadIdx.x;            // 0 .. 2^24-1
    uint32_t o0, o1;
    threefry2x32(0u, k1, 0u, j, o0, o1);
    uint32_t bits = o0 ^ o1;
    const float scale = 0.03125f;
    const float mn    = -0.015625f;
    float f = __uint_as_float((bits >> 9) | 0x3F800000u) - 1.0f;
    float v = fmaxf(mn, f * scale + mn);
    W[j] = f2bf_rne(v);
  } else {
    uint32_t base = ((b - 65536u) * 256u + threadIdx.x) * 8u;
    f32x4 a = *(const f32x4*)(x + base);
    f32x4 c = *(const f32x4*)(x + base + 4);
    union { uint16_t u[8]; bf16x8 v; } r;
    r.u[0] = f2bf_rne(a[0]); r.u[1] = f2bf_rne(a[1]);
    r.u[2] = f2bf_rne(a[2]); r.u[3] = f2bf_rne(a[3]);
    r.u[4] = f2bf_rne(c[0]); r.u[5] = f2bf_rne(c[1]);
    r.u[6] = f2bf_rne(c[2]); r.u[7] = f2bf_rne(c[3]);
    *(bf16x8*)(xb + base) = r.v;
  }
}

// ---------------------------------------------------------------------------
// 256x256 / BK=64 / 8-wave / 8-phase GEMM — round 8 changes:
//  * MFMA shape 32x32x16 (pipe 2382-2495 TF vs 16x16's 2075; m74/m101 C/D
//    layout; A: row=lane&31, k-half=lane>>5 — mirror of verified 16x16).
//  * split lgkm waits: reads in two SB0-pinned clusters; lgkm(6/2/4) ->
//    first 4 MFMAs -> lgkm(0) -> last 4 (hides half the LDS drain).
// Skeleton (stages/vmcnt/barriers/quadrants/swizzle) identical to round 7
// (proven correct): P1 (0,0) reads A0+B0 stages A1(kt+1)->buf^1;
// P2 (0,1) reads B1 stages A0(kt+2)->buf; P3 (1,1) reads A1 stages
// B0(kt+2)->buf; P4 (1,0) cached operands, stages B1(kt+2)->buf + vmcnt(6).
// LDS: linear gload_lds dest + inverse-swizzled global source; reads XOR
// byte ((row&7)<<4). Rounds 5-7 measured 0 bank conflicts.
// ---------------------------------------------------------------------------
__global__ __launch_bounds__(512, 2)
void gemm_bias_kernel(const uint16_t* __restrict__ A,   // x  bf16 [TOKENS][KIN]
                      const uint16_t* __restrict__ B,   // W  bf16 [NOUT][KIN]
                      const float* __restrict__ bias,
                      float* __restrict__ C) {
  __shared__ uint16_t smem[2][2][16384];   // [buf][A=0/B=1][32KB] = 128 KiB

  const int nwgn = NOUT / BN;                 // 16
  const int nwg  = (TOKENS / BM) * nwgn;      // 512 (divisible by 8)
  int bid = blockIdx.x;
  int cpx = nwg >> 3;
  int swzb = (bid & 7) * cpx + (bid >> 3);    // bijective XCD swizzle
  int tm = (swzb / nwgn) * BM;
  int tn = (swzb % nwgn) * BN;

  const int t    = threadIdx.x;
  const int lane = t & 63;
  const int wid  = t >> 6;       // 0..7
  const int wm   = wid >> 2;     // 0..1
  const int wn   = wid & 3;      // 0..3
  const int rrow = lane & 31;    // operand row within a 32-frag
  const int khi  = (lane >> 5) << 4;   // 16B k-offset (k-half select)

  const int swzRd = (lane & 7) << 4;                    // frag-read byte XOR
  const int lsw   = ((lane & 7) ^ (lane >> 3)) << 4;    // stage src byte offset

  f32x16 acc[4][2] = {};   // [mh*2+i2][nh]

  auto stageHalf = [&](int mat, int h, int kt, int buf) {
    const uint16_t* g = mat ? B : A;
    const int rb = (mat ? tn : tm) + h * 128 + wid * 16 + (lane >> 3);
    const char* src = (const char*)(g + (size_t)rb * KIN) + kt * 128 + lsw;
    char* dst = (char*)&smem[buf][mat][0] + h * 16384 + wid * 2048 + lane * 16;
#pragma unroll
    for (int q = 0; q < 2; ++q) {
      __builtin_amdgcn_global_load_lds(
          (const __attribute__((address_space(1))) void*)(src + (size_t)q * 8 * KIN * 2),
          (__attribute__((address_space(3))) void*)(dst + q * 1024),
          16, 0, 0);
    }
  };

#define VMW(N) asm volatile("s_waitcnt vmcnt(" #N ")" ::: "memory")
#define LKW(N) asm volatile("s_waitcnt lgkmcnt(" #N ")" ::: "memory")
#define SB0    __builtin_amdgcn_sched_barrier(0)
#define PRI(p) __builtin_amdgcn_s_setprio(p)

// 4 ds_read_b128: af[S..S+1][0..1] of half MH
#define RD_A2(Ab, MH, S)                                                       \
    _Pragma("unroll")                                                          \
    for (int ss = 0; ss < 2; ++ss)                                             \
      _Pragma("unroll")                                                        \
      for (int i2 = 0; i2 < 2; ++i2)                                           \
        af[(S) + ss][i2] = *(const bf16x8*)((Ab) +                             \
            (wm * 64 + (MH) * 128 + i2 * 32 + rrow) * 128 +                    \
            (((((S) + ss) << 5) + khi) ^ swzRd));

// 2 ds_read_b128: BV[S..S+1] of half NH
#define RD_B2(Bb, BV, NH, S)                                                   \
    _Pragma("unroll")                                                          \
    for (int ss = 0; ss < 2; ++ss)                                             \
      BV[(S) + ss] = *(const bf16x8*)((Bb) +                                   \
          (wn * 32 + (NH) * 128 + rrow) * 128 +                                \
          (((((S) + ss) << 5) + khi) ^ swzRd));

// 4 MFMA: k-steps S, S+1 for quadrant (MH,NH)
#define MF4(MH, NH, BV, S)                                                     \
    _Pragma("unroll")                                                          \
    for (int ss = 0; ss < 2; ++ss)                                             \
      _Pragma("unroll")                                                        \
      for (int i2 = 0; i2 < 2; ++i2)                                           \
        acc[(MH) * 2 + i2][NH] = __builtin_amdgcn_mfma_f32_32x32x16_bf16(      \
            af[(S) + ss][i2], BV[(S) + ss], acc[(MH) * 2 + i2][NH], 0, 0, 0);

  // MODE: 0 = main loop; 1 = kt 62 (stage A1(63) only, drain vmcnt(0) at P4);
  //       2 = kt 63 (no stages, no vm waits).
#define KTILE(BUF, KT, MODE)                                                   \
  {                                                                            \
    bf16x8 af[4][2], bv0[4], bv1[4];                                           \
    const char* Ab = (const char*)&smem[BUF][0][0];                            \
    const char* Bb = (const char*)&smem[BUF][1][0];                            \
    /* P1: (0,0); reads A0+B0 split 6/6; stage A1(kt+1)->buf^1 */              \
    RD_A2(Ab, 0, 0) RD_B2(Bb, bv0, 0, 0)                                       \
    SB0;                                                                       \
    RD_A2(Ab, 0, 2) RD_B2(Bb, bv0, 0, 2)                                       \
    if ((MODE) <= 1) stageHalf(0, 1, (KT) + 1, (BUF) ^ 1);                     \
    __builtin_amdgcn_s_barrier();                                              \
    LKW(6); SB0; PRI(1); MF4(0, 0, bv0, 0)                                     \
    LKW(0); SB0; MF4(0, 0, bv0, 2) PRI(0);                                     \
    __builtin_amdgcn_s_barrier();                                              \
    /* P2: (0,1); reads B1 split 2/2; stage A0(kt+2)->buf */                   \
    RD_B2(Bb, bv1, 1, 0)                                                       \
    SB0;                                                                       \
    RD_B2(Bb, bv1, 1, 2)                                                       \
    if ((MODE) == 0) stageHalf(0, 0, (KT) + 2, (BUF));                         \
    __builtin_amdgcn_s_barrier();                                              \
    LKW(2); SB0; PRI(1); MF4(0, 1, bv1, 0)                                     \
    LKW(0); SB0; MF4(0, 1, bv1, 2) PRI(0);                                     \
    __builtin_amdgcn_s_barrier();                                              \
    /* P3: (1,1); reads A1 split 4/4 (overwrites af); stage B0(kt+2)->buf */   \
    RD_A2(Ab, 1, 0)                                                            \
    SB0;                                                                       \
    RD_A2(Ab, 1, 2)                                                            \
    if ((MODE) == 0) stageHalf(1, 0, (KT) + 2, (BUF));                         \
    __builtin_amdgcn_s_barrier();                                              \
    LKW(4); SB0; PRI(1); MF4(1, 1, bv1, 0)                                     \
    LKW(0); SB0; MF4(1, 1, bv1, 2) PRI(0);                                     \
    __builtin_amdgcn_s_barrier();                                              \
    /* P4: (1,0); cached af(A1)+bv0(B0); stage B1(kt+2)->buf; ONE vm wait */   \
    if ((MODE) == 0) stageHalf(1, 1, (KT) + 2, (BUF));                         \
    if ((MODE) == 0) { VMW(6); } else if ((MODE) == 1) { VMW(0); }             \
    __builtin_amdgcn_s_barrier();                                              \
    PRI(1); MF4(1, 0, bv0, 0) MF4(1, 0, bv0, 2) PRI(0);                        \
    __builtin_amdgcn_s_barrier();                                              \
  }

  // Prologue (vmcnt(4) after 4 halves, vmcnt(6) after +3):
  stageHalf(0, 0, 0, 0); stageHalf(1, 0, 0, 0);
  stageHalf(0, 1, 0, 0); stageHalf(1, 1, 0, 0);
  VMW(4);
  stageHalf(0, 0, 1, 1); stageHalf(1, 0, 1, 1); stageHalf(1, 1, 1, 1);
  VMW(6);
  __builtin_amdgcn_s_barrier();

  for (int kt = 0; kt < NT - 2; kt += 2) {
    KTILE(0, kt, 0)
    KTILE(1, kt + 1, 0)
  }
  KTILE(0, 62, 1)
  KTILE(1, 63, 2)

#undef KTILE
#undef MF4
#undef RD_B2
#undef RD_A2
#undef PRI
#undef SB0
#undef LKW
#undef VMW

  // Epilogue: 32x32 C/D layout (m74/m101-verified):
  //   col = lane&31, row = (reg&3) + 8*(reg>>2) + 4*(lane>>5)
#pragma unroll
  for (int nh = 0; nh < 2; ++nh) {
    const int col = tn + wn * 32 + nh * 128 + rrow;
    const float bvs = bias[col];
#pragma unroll
    for (int mi2 = 0; mi2 < 4; ++mi2) {
      const int mh = mi2 >> 1, i2 = mi2 & 1;
      const int row0 = tm + wm * 64 + mh * 128 + i2 * 32 + ((lane >> 5) << 2);
#pragma unroll
      for (int r = 0; r < 16; ++r) {
        const int row = row0 + (r & 3) + 8 * (r >> 2);
        C[(size_t)row * NOUT + col] = acc[mi2][nh][r] + bvs;
      }
    }
  }
}

extern "C" void kernel_launch(void* const* d_in, const int* in_sizes, int n_in,
                              void* d_out, int out_size, void* d_ws, size_t ws_size,
                              hipStream_t stream) {
  const float* x    = (const float*)d_in[0];   // [8192][4096] fp32
  const float* bias = (const float*)d_in[1];   // [4096] fp32
  const int*   seed = (const int*)d_in[2];     // [1] int
  float* y = (float*)d_out;                    // [8192][4096] fp32

  // workspace: W bf16 (32 MB) | x bf16 (64 MB) — 96 MB, proven available
  uint16_t* Wb = (uint16_t*)d_ws;
  uint16_t* Xb = Wb + (size_t)NOUT * KIN;

  prep_kernel<<<65536 + 16384, 256, 0, stream>>>(x, Xb, Wb, seed);

  const int grid = (TOKENS / BM) * (NOUT / BN);   // 512
  gemm_bias_kernel<<<grid, 512, 0, stream>>>(Xb, Wb, bias, y);
}